// Round 9
// baseline (354.348 us; speedup 1.0000x reference)
//
#include <hip/hip_runtime.h>

#define SS 2048
#define DD 1024
#define HH 16
#define HD 64
#define MM 8192   // B*S

typedef unsigned short ushort_t;
typedef __attribute__((ext_vector_type(8))) short short8;
typedef __attribute__((ext_vector_type(4))) float f32x4;
typedef __attribute__((ext_vector_type(4))) unsigned short us4;
typedef __attribute__((ext_vector_type(8))) unsigned short us8;

__device__ __forceinline__ ushort_t f2bf(float f) {
    union { float f; unsigned u; } x; x.f = f;
    unsigned r = x.u + 0x7fffu + ((x.u >> 16) & 1u);
    return (ushort_t)(r >> 16);
}
__device__ __forceinline__ float bf2f(ushort_t h) {
    union { unsigned u; float f; } x; x.u = ((unsigned)h) << 16; return x.f;
}
// [hi16(b)<<16 | hi16(a)]: truncating bf16 pack of two fp32, one v_perm
__device__ __forceinline__ unsigned pack_bf2(float a, float b) {
    union { float f; unsigned u; } x, y; x.f = a; y.f = b;
    return __builtin_amdgcn_perm(y.u, x.u, 0x07060302u);
}

// async global->LDS, 16B per lane. LDS dst = wave-uniform base + lane*16.
__device__ __forceinline__ void async16(const void* g, void* l) {
    __builtin_amdgcn_global_load_lds(
        (const __attribute__((address_space(1))) unsigned int*)g,
        (__attribute__((address_space(3))) unsigned int*)l, 16, 0, 0);
}

// ---------------- cvt weights fp32 -> bf16 (8.4 MB only) ---------------------
__global__ void cvt_w(const float* __restrict__ wq, const float* __restrict__ wk,
                      const float* __restrict__ wv, const float* __restrict__ wo,
                      ushort_t* __restrict__ dst) {
    int i = (blockIdx.x * 256 + threadIdx.x) * 8;
    int w = i >> 20, j = i & 1048575;
    const float* src = (w == 0) ? wq : (w == 1) ? wk : (w == 2) ? wv : wo;
    float4 f0 = *(const float4*)(src + j);
    float4 f1 = *(const float4*)(src + j + 4);
    us8 o;
    o[0] = f2bf(f0.x); o[1] = f2bf(f0.y); o[2] = f2bf(f0.z); o[3] = f2bf(f0.w);
    o[4] = f2bf(f1.x); o[5] = f2bf(f1.y); o[6] = f2bf(f1.z); o[7] = f2bf(f1.w);
    *(us8*)(dst + i) = o;
}

// ---------------- epilogue scatter ------------------------------------------
// mode 0: bf16 [B,H,S,HD]; mode 1: bf16 [B,H,HD,S] with key-permuted S;
// mode 2: fp32 row-major [M,D]
__device__ __forceinline__ void epi_scatter(f32x4 acc[4][4], int m0, int n0,
                                            int mode, void* Yv) {
    int tid = threadIdx.x;
    int w = tid >> 6, lane = tid & 63;
    int l16 = lane & 15, quad = lane >> 4;
    int wm = (w >> 1) * 64, wn = (w & 1) * 64;
    #pragma unroll
    for (int mt = 0; mt < 4; ++mt) {
        #pragma unroll
        for (int r = 0; r < 4; ++r) {
            int row = m0 + wm + mt * 16 + quad * 4 + r;
            #pragma unroll
            for (int nt = 0; nt < 4; ++nt) {
                int col = n0 + wn + nt * 16 + l16;
                float vf = acc[mt][nt][r];
                if (mode == 2) {
                    ((float*)Yv)[(size_t)row * DD + col] = vf;
                } else {
                    ushort_t vh = f2bf(vf);
                    int b = row >> 11, s = row & 2047;
                    int h = col >> 6,  hd = col & 63;
                    if (mode == 0) {
                        ((ushort_t*)Yv)[(((size_t)b * HH + h) * SS + s) * HD + hd] = vh;
                    } else {
                        // key k = s%64 stored at pos (k&15)*4 + (k>>4)&3
                        int sp = (s & ~63) | (((s & 15) << 2) | ((s >> 4) & 3));
                        ((ushort_t*)Yv)[(((size_t)b * HH + h) * HD + hd) * SS + sp] = vh;
                    }
                }
            }
        }
    }
}

// ---------------- fused projections: fp32-A direct staging -------------------
// Eliminates the q/k/v bf16 conversion pass (-24 us of pure HBM round-trip):
// A staged as RAW fp32 via global_load_lds (zero VALU staging cost), converted
// ds_read->v_perm-pack in registers once per use (16 v_perm/iter/wave, ~50cy
// under 80cy MFMA issue — NOT r0's failure mode of redundant 8x reg-staging).
// 128^2 tile, 256t, BK=32, proven simple 2-phase sync (measured == T4).
// A fp32 tile 16KB/buf: granule pair-swizzle (pr ^ (r&3)), halves adjacent so
// b128 reads work; read-side pr = quad (since r&3 == l16&3). LDS 48KB -> 3/CU.
__global__ __launch_bounds__(256) void proj3f(const float* __restrict__ q,
                                              const float* __restrict__ k,
                                              const float* __restrict__ v,
                                              const ushort_t* __restrict__ Wall,
                                              ushort_t* __restrict__ xq,
                                              ushort_t* __restrict__ xk,
                                              ushort_t* __restrict__ xvT) {
    __shared__ __align__(16) ushort_t As[2][128 * 64];   // 128 rows x 32 fp32 = 16KB
    __shared__ __align__(16) ushort_t Bs[2][128 * 32];   // 128 rows x 32 bf16 =  8KB
    int tid = threadIdx.x;
    int w = tid >> 6, lane = tid & 63;
    int l16 = lane & 15, quad = lane >> 4;
    int mat   = (int)(blockIdx.x >> 9);
    int inner = (int)(blockIdx.x & 511);
    int m0 = (inner & 63) * 128;
    int n0 = (inner >> 6) * 128;
    const float*    A  = (mat == 0) ? q : (mat == 1) ? k : v;
    const ushort_t* Bw = Wall + ((size_t)mat << 20);
    int wm = (w >> 1) * 64, wn = (w & 1) * 64;

    f32x4 acc[4][4];
    #pragma unroll
    for (int i = 0; i < 4; ++i)
        #pragma unroll
        for (int j = 0; j < 4; ++j) acc[i][j] = (f32x4){0.f, 0.f, 0.f, 0.f};

    // A: 1024 granules (16B = 4 fp32), 4 per thread. granule g of row r at
    // in-row pair position (pr ^ (r&3)), half preserved.
    int ra[4], ca[4];
    #pragma unroll
    for (int kgi = 0; kgi < 4; ++kgi) {
        int g = tid + 256 * kgi;
        int r = g >> 3, gi = g & 7;
        int gis = (((gi >> 1) ^ (r & 3)) << 1) | (gi & 1);
        ra[kgi] = r; ca[kgi] = gis * 4;            // float offset in 32-col stripe
    }
    // B: 512 granules, 2 per thread (4 granules/row, XOR r&3) — proven path.
    int rb0 = tid >> 2,          jb0 = ((tid & 3) ^ (rb0 & 3)) * 8;
    int gb1 = tid + 256;
    int rb1 = gb1 >> 2,          jb1 = ((gb1 & 3) ^ (rb1 & 3)) * 8;
    int swA = (quad ^ (l16 & 3)) * 16;             // ushort offset of A pair
    int swB = (quad ^ (l16 & 3)) * 8;

    // prologue: stage kk=0 into buf0
    #pragma unroll
    for (int kgi = 0; kgi < 4; ++kgi)
        async16(A + (size_t)(m0 + ra[kgi]) * DD + ca[kgi], &As[0][(tid + 256 * kgi) * 8]);
    async16(Bw + (size_t)(n0 + rb0) * DD + jb0, &Bs[0][(size_t)(w * 64) * 8]);
    async16(Bw + (size_t)(n0 + rb1) * DD + jb1, &Bs[0][(size_t)(256 + w * 64) * 8]);

    for (int kk = 0; kk < 32; ++kk) {
        int c = kk & 1;
        __syncthreads();
        if (kk < 31) {
            int k1 = (kk + 1) * 32;
            #pragma unroll
            for (int kgi = 0; kgi < 4; ++kgi)
                async16(A + (size_t)(m0 + ra[kgi]) * DD + k1 + ca[kgi],
                        &As[c ^ 1][(tid + 256 * kgi) * 8]);
            async16(Bw + (size_t)(n0 + rb0) * DD + k1 + jb0, &Bs[c ^ 1][(size_t)(w * 64) * 8]);
            async16(Bw + (size_t)(n0 + rb1) * DD + k1 + jb1, &Bs[c ^ 1][(size_t)(256 + w * 64) * 8]);
        }
        short8 af[4], bfr[4];
        #pragma unroll
        for (int t = 0; t < 4; ++t) {
            int rowA = (wm + t * 16 + l16) * 64 + swA;   // 64 ushorts per fp32 row
            f32x4 fa0 = *(const f32x4*)&As[c][rowA];
            f32x4 fa1 = *(const f32x4*)&As[c][rowA + 8];
            union { uint4 u; short8 s; } cv;
            cv.u.x = pack_bf2(fa0[0], fa0[1]);
            cv.u.y = pack_bf2(fa0[2], fa0[3]);
            cv.u.z = pack_bf2(fa1[0], fa1[1]);
            cv.u.w = pack_bf2(fa1[2], fa1[3]);
            af[t]  = cv.s;
            bfr[t] = *(const short8*)&Bs[c][(wn + t * 16 + l16) * 32 + swB];
        }
        #pragma unroll
        for (int mt = 0; mt < 4; ++mt)
            #pragma unroll
            for (int nt = 0; nt < 4; ++nt)
                acc[mt][nt] = __builtin_amdgcn_mfma_f32_16x16x32_bf16(af[mt], bfr[nt], acc[mt][nt], 0, 0, 0);
    }

    void* Y = (mat == 0) ? (void*)xq : (mat == 1) ? (void*)xk : (void*)xvT;
    epi_scatter(acc, m0, n0, (mat == 2) ? 1 : 0, Y);
}

// ---------------- output GEMM: 256x128 tile, 2-phase, 8 waves ----------------
__global__ __launch_bounds__(512) void out_gemm(const ushort_t* __restrict__ Abf,
                                                const ushort_t* __restrict__ Bw,
                                                float* __restrict__ Y) {
    __shared__ __align__(16) ushort_t As[2][256 * 32];
    __shared__ __align__(16) ushort_t Bs[2][128 * 32];
    int tid = threadIdx.x;
    int w = tid >> 6, lane = tid & 63;
    int l16 = lane & 15, quad = lane >> 4;
    int inner = (int)blockIdx.x;
    int m0 = (inner & 31) * 256;
    int n0 = (inner >> 5) * 128;
    int wm = (w >> 1) * 64, wn = (w & 1) * 64;

    f32x4 acc[4][4];
    #pragma unroll
    for (int i = 0; i < 4; ++i)
        #pragma unroll
        for (int j = 0; j < 4; ++j) acc[i][j] = (f32x4){0.f, 0.f, 0.f, 0.f};

    int ra0 = tid >> 2,           ja0 = ((tid & 3) ^ (ra0 & 3)) * 8;
    int ga1 = tid + 512;
    int ra1 = ga1 >> 2,           ja1 = ((ga1 & 3) ^ (ra1 & 3)) * 8;
    int rb  = tid >> 2,           jb  = ((tid & 3) ^ (rb & 3)) * 8;
    int swA = (quad ^ (l16 & 3)) * 8;

    async16(Abf + (size_t)(m0 + ra0) * DD + ja0, &As[0][(size_t)(w * 64) * 8]);
    async16(Abf + (size_t)(m0 + ra1) * DD + ja1, &As[0][(size_t)(512 + w * 64) * 8]);
    async16(Bw  + (size_t)(n0 + rb)  * DD + jb,  &Bs[0][(size_t)(w * 64) * 8]);

    for (int kk = 0; kk < 32; ++kk) {
        int c = kk & 1;
        __syncthreads();
        if (kk < 31) {
            int k1 = (kk + 1) * 32;
            async16(Abf + (size_t)(m0 + ra0) * DD + k1 + ja0, &As[c ^ 1][(size_t)(w * 64) * 8]);
            async16(Abf + (size_t)(m0 + ra1) * DD + k1 + ja1, &As[c ^ 1][(size_t)(512 + w * 64) * 8]);
            async16(Bw  + (size_t)(n0 + rb)  * DD + k1 + jb,  &Bs[c ^ 1][(size_t)(w * 64) * 8]);
        }
        short8 af[4], bfr[4];
        #pragma unroll
        for (int t = 0; t < 4; ++t) {
            af[t]  = *(const short8*)&As[c][(wm + t * 16 + l16) * 32 + swA];
            bfr[t] = *(const short8*)&Bs[c][(wn + t * 16 + l16) * 32 + swA];
        }
        #pragma unroll
        for (int mt = 0; mt < 4; ++mt)
            #pragma unroll
            for (int nt = 0; nt < 4; ++nt)
                acc[mt][nt] = __builtin_amdgcn_mfma_f32_16x16x32_bf16(af[mt], bfr[nt], acc[mt][nt], 0, 0, 0);
    }
    epi_scatter(acc, m0, n0, 2, Y);
}

// ---------------- Flash attention: QBLK=128, 8 waves (r6-proven) -------------
// 512 blocks x 512 threads; 8 waves each own 16 q-rows; K/V tile staged once
// per 128 q-rows, double-buffered, 1 barrier/kt. bh&7 = XCD locality.
// (r7 direct-L2 failed: staging dedups K/V across the 8 waves. r8 4-wave
// reuse variant failed its prediction — reverted to this proven form.)
__global__ __launch_bounds__(512) void attn_kernel(const ushort_t* __restrict__ xq,
                                                   const ushort_t* __restrict__ xk,
                                                   const ushort_t* __restrict__ xvT,
                                                   ushort_t* __restrict__ ao) {
    __shared__ __align__(16) ushort_t Ksm[2][64 * 64];
    __shared__ __align__(16) ushort_t Vsm[2][64 * 64];
    __shared__ __align__(16) ushort_t Psm[8][16 * 72];

    int tid = threadIdx.x;
    int w = tid >> 6, lane = tid & 63;
    int l16 = lane & 15, quad = lane >> 4;
    int bh = blockIdx.x & 63;
    int p  = blockIdx.x >> 6;          // 0..7
    int b = bh >> 4, h = bh & 15;

    const ushort_t* Q  = xq  + (size_t)bh * SS * HD;
    const ushort_t* K  = xk  + (size_t)bh * SS * HD;
    const ushort_t* VT = xvT + (size_t)bh * HD * SS;

    // staging: 512 threads x 1 granule = 64 rows x 8 granules (16B each)
    int r0 = tid >> 3, j0 = ((tid & 7) ^ (r0 & 7)) * 8;
    int ldsb = (w * 64) * 8;           // wave-uniform LDS base (lane*16B implied)

    short8 ones;
    #pragma unroll
    for (int i = 0; i < 8; ++i) ones[i] = (short)0x3F80;   // bf16 1.0

    const float CS = 0.125f * 1.44269504f;   // scale * log2(e), folded into Q

    for (int ph = 0; ph < 2; ++ph) {
        int qt = ph ? (15 - p) : p;    // 128-row q-tile index, 0..15
        int qb = qt * 128;
        int qmin = qb + w * 16;
        int ktmax = 2 * qt + 1;        // last 64-key tile touching this q-tile

        // Q fragments pre-scaled by CS
        short8 aq[2];
        #pragma unroll
        for (int kc = 0; kc < 2; ++kc) {
            short8 t = *(const short8*)(Q + (size_t)(qmin + l16) * HD + kc * 32 + quad * 8);
            #pragma unroll
            for (int i = 0; i < 8; ++i)
                t[i] = (short)f2bf(bf2f((ushort_t)t[i]) * CS);
            aq[kc] = t;
        }

        f32x4 o[4];
        #pragma unroll
        for (int dt = 0; dt < 4; ++dt) o[dt] = (f32x4){0.f, 0.f, 0.f, 0.f};
        f32x4 lacc = (f32x4){0.f, 0.f, 0.f, 0.f};

        __syncthreads();   // prev phase readers done before re-staging buf 0
        async16(K  + (size_t)r0 * HD + j0, &Ksm[0][ldsb]);
        async16(VT + (size_t)r0 * SS + j0, &Vsm[0][ldsb]);

        for (int kt = 0; kt <= ktmax; ++kt) {
            int kb = kt * 64;
            int c = kt & 1;
            __syncthreads();                    // stage(kt) published
            if (kt < ktmax) {                   // prefetch kt+1 into other buffer
                int kb1 = kb + 64;
                async16(K  + (size_t)(kb1 + r0) * HD + j0, &Ksm[c ^ 1][ldsb]);
                async16(VT + (size_t)r0 * SS + kb1 + j0, &Vsm[c ^ 1][ldsb]);
            }

            // ---- scores = (CS*Q) . K^T (log2 domain) ----
            f32x4 sc[4];
            __builtin_amdgcn_s_setprio(1);
            #pragma unroll
            for (int nt = 0; nt < 4; ++nt) {
                int row = nt * 16 + l16;
                short8 bk0 = *(const short8*)&Ksm[c][row * 64 + ((0 + quad) ^ (l16 & 7)) * 8];
                short8 bk1 = *(const short8*)&Ksm[c][row * 64 + ((4 + quad) ^ (l16 & 7)) * 8];
                f32x4 cc = (f32x4){0.f, 0.f, 0.f, 0.f};
                cc = __builtin_amdgcn_mfma_f32_16x16x32_bf16(aq[0], bk0, cc, 0, 0, 0);
                cc = __builtin_amdgcn_mfma_f32_16x16x32_bf16(aq[1], bk1, cc, 0, 0, 0);
                sc[nt] = cc;
            }
            __builtin_amdgcn_s_setprio(0);

            // ---- softmax numerators, fixed max=0 (scores bounded ~|5|) ----
            bool msk = (kb + 63 > qmin);
            #pragma unroll
            for (int r = 0; r < 4; ++r) {
                float e0, e1, e2, e3;
                if (msk) {
                    int qg = qmin + quad * 4 + r;
                    e0 = (kb +  0 + l16 <= qg) ? __builtin_amdgcn_exp2f(sc[0][r]) : 0.f;
                    e1 = (kb + 16 + l16 <= qg) ? __builtin_amdgcn_exp2f(sc[1][r]) : 0.f;
                    e2 = (kb + 32 + l16 <= qg) ? __builtin_amdgcn_exp2f(sc[2][r]) : 0.f;
                    e3 = (kb + 48 + l16 <= qg) ? __builtin_amdgcn_exp2f(sc[3][r]) : 0.f;
                } else {
                    e0 = __builtin_amdgcn_exp2f(sc[0][r]);
                    e1 = __builtin_amdgcn_exp2f(sc[1][r]);
                    e2 = __builtin_amdgcn_exp2f(sc[2][r]);
                    e3 = __builtin_amdgcn_exp2f(sc[3][r]);
                }
                uint2 pk = { pack_bf2(e0, e1), pack_bf2(e2, e3) };
                *(uint2*)&Psm[w][(quad * 4 + r) * 72 + l16 * 4] = pk;
            }

            // per-wave P scratch: drain DS writes before reads (no barrier)
            asm volatile("s_waitcnt lgkmcnt(0)" ::: "memory");

            // ---- O += P . V ; l += P . 1 (V in permuted key order) ----
            __builtin_amdgcn_s_setprio(1);
            #pragma unroll
            for (int kc = 0; kc < 2; ++kc) {
                short8 ap = *(const short8*)&Psm[w][l16 * 72 + kc * 32 + quad * 8];
                lacc = __builtin_amdgcn_mfma_f32_16x16x32_bf16(ap, ones, lacc, 0, 0, 0);
                #pragma unroll
                for (int dt = 0; dt < 4; ++dt) {
                    int row = dt * 16 + l16;
                    short8 bv = *(const short8*)&Vsm[c][row * 64 + ((kc * 4 + quad) ^ (l16 & 7)) * 8];
                    o[dt] = __builtin_amdgcn_mfma_f32_16x16x32_bf16(ap, bv, o[dt], 0, 0, 0);
                }
            }
            __builtin_amdgcn_s_setprio(0);
        }

        // ---- epilogue: normalize by MFMA row sums, store bf16 ----
        #pragma unroll
        for (int r = 0; r < 4; ++r) {
            float inv = 1.0f / lacc[r];
            int qg = qmin + quad * 4 + r;
            #pragma unroll
            for (int dt = 0; dt < 4; ++dt)
                ao[((size_t)(b * SS + qg)) * DD + h * HD + dt * 16 + l16] = f2bf(o[dt][r] * inv);
        }
    }
}

// ---------------------------------------------------------------------------
extern "C" void kernel_launch(void* const* d_in, const int* in_sizes, int n_in,
                              void* d_out, int out_size, void* d_ws, size_t ws_size,
                              hipStream_t stream) {
    const float* q  = (const float*)d_in[0];
    const float* k  = (const float*)d_in[1];
    const float* v  = (const float*)d_in[2];
    const float* wq = (const float*)d_in[3];
    const float* wk = (const float*)d_in[4];
    const float* wv = (const float*)d_in[5];
    const float* wo = (const float*)d_in[6];
    float* out = (float*)d_out;

    // ws (halves): wbf[4M] | xq[8M] | xk[8M] | xvT[8M] | ao[8M] = 72 MB.
    ushort_t* wbf = (ushort_t*)d_ws;
    ushort_t* xq  = wbf + 4194304ull;
    ushort_t* xk  = xq  + 8388608ull;
    ushort_t* xvT = xk  + 8388608ull;
    ushort_t* ao  = xvT + 8388608ull;

    cvt_w<<<2048, 256, 0, stream>>>(wq, wk, wv, wo, wbf);
    proj3f<<<1536, 256, 0, stream>>>(q, k, v, wbf, xq, xk, xvT);
    attn_kernel<<<512, 512, 0, stream>>>(xq, xk, xvT, ao);
    out_gemm<<<256, 512, 0, stream>>>(ao, wbf + 3145728ull, out);
}

// Round 10
// 322.890 us; speedup vs baseline: 1.0974x; 1.0974x over previous
//
#include <hip/hip_runtime.h>

#define SS 2048
#define DD 1024
#define HH 16
#define HD 64
#define MM 8192   // B*S

typedef unsigned short ushort_t;
typedef __attribute__((ext_vector_type(8))) short short8;
typedef __attribute__((ext_vector_type(4))) float f32x4;
typedef __attribute__((ext_vector_type(4))) unsigned short us4;
typedef __attribute__((ext_vector_type(8))) unsigned short us8;

__device__ __forceinline__ ushort_t f2bf(float f) {
    union { float f; unsigned u; } x; x.f = f;
    unsigned r = x.u + 0x7fffu + ((x.u >> 16) & 1u);
    return (ushort_t)(r >> 16);
}
__device__ __forceinline__ float bf2f(ushort_t h) {
    union { unsigned u; float f; } x; x.u = ((unsigned)h) << 16; return x.f;
}
// [hi16(b)<<16 | hi16(a)]: truncating bf16 pack of two fp32, one v_perm
__device__ __forceinline__ unsigned pack_bf2(float a, float b) {
    union { float f; unsigned u; } x, y; x.f = a; y.f = b;
    return __builtin_amdgcn_perm(y.u, x.u, 0x07060302u);
}

// async global->LDS, 16B per lane. LDS dst = wave-uniform base + lane*16.
__device__ __forceinline__ void async16(const void* g, void* l) {
    __builtin_amdgcn_global_load_lds(
        (const __attribute__((address_space(1))) unsigned int*)g,
        (__attribute__((address_space(3))) unsigned int*)l, 16, 0, 0);
}

// ---------------- cvt fp32 -> bf16: q,k,v (8M each) + 4 weights (1M each) ----
// Dedicated memory-bound pass. r0 (in-GEMM redundant cvt) and r9 (in-GEMM
// fp32-A staging) both lost more in VALU/LDS pipes than this 24us HBM
// round-trip costs — conversion stays here permanently.
__global__ void cvt_all(const float* __restrict__ q, const float* __restrict__ k,
                        const float* __restrict__ v, const float* __restrict__ wq,
                        const float* __restrict__ wk, const float* __restrict__ wv,
                        const float* __restrict__ wo, ushort_t* __restrict__ qbf,
                        ushort_t* __restrict__ kbf, ushort_t* __restrict__ vbf,
                        ushort_t* __restrict__ wbf) {
    long i = ((long)blockIdx.x * 256 + threadIdx.x) * 8;
    const float* src; ushort_t* dst;
    if (i < (3l << 23)) {
        int s = (int)(i >> 23);
        long off = i & ((1l << 23) - 1);
        src = ((s == 0) ? q : (s == 1) ? k : v) + off;
        dst = ((s == 0) ? qbf : (s == 1) ? kbf : vbf) + off;
    } else {
        long j = i - (3l << 23);
        int s = (int)(j >> 20);
        src = ((s == 0) ? wq : (s == 1) ? wk : (s == 2) ? wv : wo) + (j & 1048575);
        dst = wbf + j;
    }
    float4 f0 = *(const float4*)src;
    float4 f1 = *(const float4*)(src + 4);
    us8 o;
    o[0] = f2bf(f0.x); o[1] = f2bf(f0.y); o[2] = f2bf(f0.z); o[3] = f2bf(f0.w);
    o[4] = f2bf(f1.x); o[5] = f2bf(f1.y); o[6] = f2bf(f1.z); o[7] = f2bf(f1.w);
    *(us8*)dst = o;
}

// ---------------- epilogue scatter ------------------------------------------
// mode 0: bf16 [B,H,S,HD]; mode 1: bf16 [B,H,HD,S] with key-permuted S;
// mode 2: fp32 row-major [M,D]
__device__ __forceinline__ void epi_scatter(f32x4 acc[4][4], int m0, int n0,
                                            int mode, void* Yv) {
    int tid = threadIdx.x;
    int w = tid >> 6, lane = tid & 63;
    int l16 = lane & 15, quad = lane >> 4;
    int wm = (w >> 1) * 64, wn = (w & 1) * 64;
    #pragma unroll
    for (int mt = 0; mt < 4; ++mt) {
        #pragma unroll
        for (int r = 0; r < 4; ++r) {
            int row = m0 + wm + mt * 16 + quad * 4 + r;
            #pragma unroll
            for (int nt = 0; nt < 4; ++nt) {
                int col = n0 + wn + nt * 16 + l16;
                float vf = acc[mt][nt][r];
                if (mode == 2) {
                    ((float*)Yv)[(size_t)row * DD + col] = vf;
                } else {
                    ushort_t vh = f2bf(vf);
                    int b = row >> 11, s = row & 2047;
                    int h = col >> 6,  hd = col & 63;
                    if (mode == 0) {
                        ((ushort_t*)Yv)[(((size_t)b * HH + h) * SS + s) * HD + hd] = vh;
                    } else {
                        // key k = s%64 stored at pos (k&15)*4 + (k>>4)&3
                        int sp = (s & ~63) | (((s & 15) << 2) | ((s >> 4) & 3));
                        ((ushort_t*)Yv)[(((size_t)b * HH + h) * HD + hd) * SS + sp] = vh;
                    }
                }
            }
        }
    }
}

// ---------------- fused projections: T4 counted-vmcnt pipeline ---------------
// 128^2 tile, 256 threads, BK=32, pure bf16. r5/r6 verified ~101 us.
// Structural plateau for this K=1024 shape: 2-buf drain, 3-buf counted,
// 256-row tile, fp32-A staging all measured 100-177; this is the best.
__global__ __launch_bounds__(256) void proj3f(const ushort_t* __restrict__ qbf,
                                              const ushort_t* __restrict__ kbf,
                                              const ushort_t* __restrict__ vbf,
                                              const ushort_t* __restrict__ Wall,
                                              ushort_t* __restrict__ xq,
                                              ushort_t* __restrict__ xk,
                                              ushort_t* __restrict__ xvT) {
    __shared__ __align__(16) ushort_t As[3][128 * 32];
    __shared__ __align__(16) ushort_t Bs[3][128 * 32];
    int tid = threadIdx.x;
    int w = tid >> 6, lane = tid & 63;
    int l16 = lane & 15, quad = lane >> 4;
    int mat   = (int)(blockIdx.x >> 9);
    int inner = (int)(blockIdx.x & 511);
    int m0 = (inner & 63) * 128;
    int n0 = (inner >> 6) * 128;
    const ushort_t* A  = (mat == 0) ? qbf : (mat == 1) ? kbf : vbf;
    const ushort_t* Bw = Wall + ((size_t)mat << 20);
    int wm = (w >> 1) * 64, wn = (w & 1) * 64;

    f32x4 acc[4][4];
    #pragma unroll
    for (int i = 0; i < 4; ++i)
        #pragma unroll
        for (int j = 0; j < 4; ++j) acc[i][j] = (f32x4){0.f, 0.f, 0.f, 0.f};

    int g0 = w * 64 + lane, r0 = g0 >> 2, j0 = ((g0 & 3) ^ (r0 & 3)) * 8;
    int g1 = g0 + 256,      r1 = g1 >> 2, j1 = ((g1 & 3) ^ (r1 & 3)) * 8;
    int swA = (quad ^ (l16 & 3)) * 8;

    const ushort_t* Ar0 = A  + (size_t)(m0 + r0) * DD + j0;
    const ushort_t* Ar1 = A  + (size_t)(m0 + r1) * DD + j1;
    const ushort_t* Br0 = Bw + (size_t)(n0 + r0) * DD + j0;
    const ushort_t* Br1 = Bw + (size_t)(n0 + r1) * DD + j1;
    int ldsA0 = w * 64 * 8, ldsA1 = (256 + w * 64) * 8;

    // prologue: stage k=0 -> buf0, k=1 -> buf1 (8 loads outstanding)
    async16(Ar0,      &As[0][ldsA0]);
    async16(Ar1,      &As[0][ldsA1]);
    async16(Br0,      &Bs[0][ldsA0]);
    async16(Br1,      &Bs[0][ldsA1]);
    async16(Ar0 + 32, &As[1][ldsA0]);
    async16(Ar1 + 32, &As[1][ldsA1]);
    async16(Br0 + 32, &Bs[1][ldsA0]);
    async16(Br1 + 32, &Bs[1][ldsA1]);

    int c = 0, c2 = 2;   // compute buffer, stage-target buffer (= c+2 mod 3)
    for (int kk = 0; kk < 32; ++kk) {
        __builtin_amdgcn_s_barrier();          // iter kk-1 readers of buf c2 done
        if (kk < 30) {
            int k2 = (kk + 2) * 32;
            async16(Ar0 + k2, &As[c2][ldsA0]);
            async16(Ar1 + k2, &As[c2][ldsA1]);
            async16(Br0 + k2, &Bs[c2][ldsA0]);
            async16(Br1 + k2, &Bs[c2][ldsA1]);
            asm volatile("s_waitcnt vmcnt(8)" ::: "memory");   // stage(kk) landed
        } else if (kk == 30) {
            asm volatile("s_waitcnt vmcnt(4)" ::: "memory");
        } else {
            asm volatile("s_waitcnt vmcnt(0)" ::: "memory");
        }
        __builtin_amdgcn_s_barrier();          // ALL waves' stage(kk) landed
        __builtin_amdgcn_sched_barrier(0);

        short8 af[4], bfr[4];
        #pragma unroll
        for (int t = 0; t < 4; ++t) {
            af[t]  = *(const short8*)&As[c][(wm + t * 16 + l16) * 32 + swA];
            bfr[t] = *(const short8*)&Bs[c][(wn + t * 16 + l16) * 32 + swA];
        }
        #pragma unroll
        for (int mt = 0; mt < 4; ++mt)
            #pragma unroll
            for (int nt = 0; nt < 4; ++nt)
                acc[mt][nt] = __builtin_amdgcn_mfma_f32_16x16x32_bf16(af[mt], bfr[nt], acc[mt][nt], 0, 0, 0);

        c  = (c  == 2) ? 0 : c  + 1;
        c2 = (c2 == 2) ? 0 : c2 + 1;
    }

    void* Y = (mat == 0) ? (void*)xq : (mat == 1) ? (void*)xk : (void*)xvT;
    epi_scatter(acc, m0, n0, (mat == 2) ? 1 : 0, Y);
}

// ---------------- output GEMM: 256x128 tile, 2-phase, 8 waves ----------------
__global__ __launch_bounds__(512) void out_gemm(const ushort_t* __restrict__ Abf,
                                                const ushort_t* __restrict__ Bw,
                                                float* __restrict__ Y) {
    __shared__ __align__(16) ushort_t As[2][256 * 32];
    __shared__ __align__(16) ushort_t Bs[2][128 * 32];
    int tid = threadIdx.x;
    int w = tid >> 6, lane = tid & 63;
    int l16 = lane & 15, quad = lane >> 4;
    int inner = (int)blockIdx.x;
    int m0 = (inner & 31) * 256;
    int n0 = (inner >> 5) * 128;
    int wm = (w >> 1) * 64, wn = (w & 1) * 64;

    f32x4 acc[4][4];
    #pragma unroll
    for (int i = 0; i < 4; ++i)
        #pragma unroll
        for (int j = 0; j < 4; ++j) acc[i][j] = (f32x4){0.f, 0.f, 0.f, 0.f};

    int ra0 = tid >> 2,           ja0 = ((tid & 3) ^ (ra0 & 3)) * 8;
    int ga1 = tid + 512;
    int ra1 = ga1 >> 2,           ja1 = ((ga1 & 3) ^ (ra1 & 3)) * 8;
    int rb  = tid >> 2,           jb  = ((tid & 3) ^ (rb & 3)) * 8;
    int swA = (quad ^ (l16 & 3)) * 8;

    async16(Abf + (size_t)(m0 + ra0) * DD + ja0, &As[0][(size_t)(w * 64) * 8]);
    async16(Abf + (size_t)(m0 + ra1) * DD + ja1, &As[0][(size_t)(512 + w * 64) * 8]);
    async16(Bw  + (size_t)(n0 + rb)  * DD + jb,  &Bs[0][(size_t)(w * 64) * 8]);

    for (int kk = 0; kk < 32; ++kk) {
        int c = kk & 1;
        __syncthreads();
        if (kk < 31) {
            int k1 = (kk + 1) * 32;
            async16(Abf + (size_t)(m0 + ra0) * DD + k1 + ja0, &As[c ^ 1][(size_t)(w * 64) * 8]);
            async16(Abf + (size_t)(m0 + ra1) * DD + k1 + ja1, &As[c ^ 1][(size_t)(512 + w * 64) * 8]);
            async16(Bw  + (size_t)(n0 + rb)  * DD + k1 + jb,  &Bs[c ^ 1][(size_t)(w * 64) * 8]);
        }
        short8 af[4], bfr[4];
        #pragma unroll
        for (int t = 0; t < 4; ++t) {
            af[t]  = *(const short8*)&As[c][(wm + t * 16 + l16) * 32 + swA];
            bfr[t] = *(const short8*)&Bs[c][(wn + t * 16 + l16) * 32 + swA];
        }
        #pragma unroll
        for (int mt = 0; mt < 4; ++mt)
            #pragma unroll
            for (int nt = 0; nt < 4; ++nt)
                acc[mt][nt] = __builtin_amdgcn_mfma_f32_16x16x32_bf16(af[mt], bfr[nt], acc[mt][nt], 0, 0, 0);
    }
    epi_scatter(acc, m0, n0, 2, Y);
}

// ---------------- Flash attention: QBLK=128, 8 waves (r6-proven) -------------
// 512 blocks x 512 threads; 8 waves each own 16 q-rows; K/V tile staged once
// per 128 q-rows, double-buffered, 1 barrier/kt. bh&7 = XCD locality.
// (r7 direct-L2 failed 2.6x: staging dedups K/V across the 8 waves.
// r8 4-wave K/V-reuse variant: neutral-to-negative, reverted.)
__global__ __launch_bounds__(512) void attn_kernel(const ushort_t* __restrict__ xq,
                                                   const ushort_t* __restrict__ xk,
                                                   const ushort_t* __restrict__ xvT,
                                                   ushort_t* __restrict__ ao) {
    __shared__ __align__(16) ushort_t Ksm[2][64 * 64];
    __shared__ __align__(16) ushort_t Vsm[2][64 * 64];
    __shared__ __align__(16) ushort_t Psm[8][16 * 72];

    int tid = threadIdx.x;
    int w = tid >> 6, lane = tid & 63;
    int l16 = lane & 15, quad = lane >> 4;
    int bh = blockIdx.x & 63;
    int p  = blockIdx.x >> 6;          // 0..7
    int b = bh >> 4, h = bh & 15;

    const ushort_t* Q  = xq  + (size_t)bh * SS * HD;
    const ushort_t* K  = xk  + (size_t)bh * SS * HD;
    const ushort_t* VT = xvT + (size_t)bh * HD * SS;

    // staging: 512 threads x 1 granule = 64 rows x 8 granules (16B each)
    int r0 = tid >> 3, j0 = ((tid & 7) ^ (r0 & 7)) * 8;
    int ldsb = (w * 64) * 8;           // wave-uniform LDS base (lane*16B implied)

    short8 ones;
    #pragma unroll
    for (int i = 0; i < 8; ++i) ones[i] = (short)0x3F80;   // bf16 1.0

    const float CS = 0.125f * 1.44269504f;   // scale * log2(e), folded into Q

    for (int ph = 0; ph < 2; ++ph) {
        int qt = ph ? (15 - p) : p;    // 128-row q-tile index, 0..15
        int qb = qt * 128;
        int qmin = qb + w * 16;
        int ktmax = 2 * qt + 1;        // last 64-key tile touching this q-tile

        // Q fragments pre-scaled by CS
        short8 aq[2];
        #pragma unroll
        for (int kc = 0; kc < 2; ++kc) {
            short8 t = *(const short8*)(Q + (size_t)(qmin + l16) * HD + kc * 32 + quad * 8);
            #pragma unroll
            for (int i = 0; i < 8; ++i)
                t[i] = (short)f2bf(bf2f((ushort_t)t[i]) * CS);
            aq[kc] = t;
        }

        f32x4 o[4];
        #pragma unroll
        for (int dt = 0; dt < 4; ++dt) o[dt] = (f32x4){0.f, 0.f, 0.f, 0.f};
        f32x4 lacc = (f32x4){0.f, 0.f, 0.f, 0.f};

        __syncthreads();   // prev phase readers done before re-staging buf 0
        async16(K  + (size_t)r0 * HD + j0, &Ksm[0][ldsb]);
        async16(VT + (size_t)r0 * SS + j0, &Vsm[0][ldsb]);

        for (int kt = 0; kt <= ktmax; ++kt) {
            int kb = kt * 64;
            int c = kt & 1;
            __syncthreads();                    // stage(kt) published
            if (kt < ktmax) {                   // prefetch kt+1 into other buffer
                int kb1 = kb + 64;
                async16(K  + (size_t)(kb1 + r0) * HD + j0, &Ksm[c ^ 1][ldsb]);
                async16(VT + (size_t)r0 * SS + kb1 + j0, &Vsm[c ^ 1][ldsb]);
            }

            // ---- scores = (CS*Q) . K^T (log2 domain) ----
            f32x4 sc[4];
            __builtin_amdgcn_s_setprio(1);
            #pragma unroll
            for (int nt = 0; nt < 4; ++nt) {
                int row = nt * 16 + l16;
                short8 bk0 = *(const short8*)&Ksm[c][row * 64 + ((0 + quad) ^ (l16 & 7)) * 8];
                short8 bk1 = *(const short8*)&Ksm[c][row * 64 + ((4 + quad) ^ (l16 & 7)) * 8];
                f32x4 cc = (f32x4){0.f, 0.f, 0.f, 0.f};
                cc = __builtin_amdgcn_mfma_f32_16x16x32_bf16(aq[0], bk0, cc, 0, 0, 0);
                cc = __builtin_amdgcn_mfma_f32_16x16x32_bf16(aq[1], bk1, cc, 0, 0, 0);
                sc[nt] = cc;
            }
            __builtin_amdgcn_s_setprio(0);

            // ---- softmax numerators, fixed max=0 (scores bounded ~|5|) ----
            bool msk = (kb + 63 > qmin);
            #pragma unroll
            for (int r = 0; r < 4; ++r) {
                float e0, e1, e2, e3;
                if (msk) {
                    int qg = qmin + quad * 4 + r;
                    e0 = (kb +  0 + l16 <= qg) ? __builtin_amdgcn_exp2f(sc[0][r]) : 0.f;
                    e1 = (kb + 16 + l16 <= qg) ? __builtin_amdgcn_exp2f(sc[1][r]) : 0.f;
                    e2 = (kb + 32 + l16 <= qg) ? __builtin_amdgcn_exp2f(sc[2][r]) : 0.f;
                    e3 = (kb + 48 + l16 <= qg) ? __builtin_amdgcn_exp2f(sc[3][r]) : 0.f;
                } else {
                    e0 = __builtin_amdgcn_exp2f(sc[0][r]);
                    e1 = __builtin_amdgcn_exp2f(sc[1][r]);
                    e2 = __builtin_amdgcn_exp2f(sc[2][r]);
                    e3 = __builtin_amdgcn_exp2f(sc[3][r]);
                }
                uint2 pk = { pack_bf2(e0, e1), pack_bf2(e2, e3) };
                *(uint2*)&Psm[w][(quad * 4 + r) * 72 + l16 * 4] = pk;
            }

            // per-wave P scratch: drain DS writes before reads (no barrier)
            asm volatile("s_waitcnt lgkmcnt(0)" ::: "memory");

            // ---- O += P . V ; l += P . 1 (V in permuted key order) ----
            __builtin_amdgcn_s_setprio(1);
            #pragma unroll
            for (int kc = 0; kc < 2; ++kc) {
                short8 ap = *(const short8*)&Psm[w][l16 * 72 + kc * 32 + quad * 8];
                lacc = __builtin_amdgcn_mfma_f32_16x16x32_bf16(ap, ones, lacc, 0, 0, 0);
                #pragma unroll
                for (int dt = 0; dt < 4; ++dt) {
                    int row = dt * 16 + l16;
                    short8 bv = *(const short8*)&Vsm[c][row * 64 + ((kc * 4 + quad) ^ (l16 & 7)) * 8];
                    o[dt] = __builtin_amdgcn_mfma_f32_16x16x32_bf16(ap, bv, o[dt], 0, 0, 0);
                }
            }
            __builtin_amdgcn_s_setprio(0);
        }

        // ---- epilogue: normalize by MFMA row sums, store bf16 ----
        #pragma unroll
        for (int r = 0; r < 4; ++r) {
            float inv = 1.0f / lacc[r];
            int qg = qmin + quad * 4 + r;
            #pragma unroll
            for (int dt = 0; dt < 4; ++dt)
                ao[((size_t)(b * SS + qg)) * DD + h * HD + dt * 16 + l16] = f2bf(o[dt][r] * inv);
        }
    }
}

// ---------------------------------------------------------------------------
extern "C" void kernel_launch(void* const* d_in, const int* in_sizes, int n_in,
                              void* d_out, int out_size, void* d_ws, size_t ws_size,
                              hipStream_t stream) {
    const float* q  = (const float*)d_in[0];
    const float* k  = (const float*)d_in[1];
    const float* v  = (const float*)d_in[2];
    const float* wq = (const float*)d_in[3];
    const float* wk = (const float*)d_in[4];
    const float* wv = (const float*)d_in[5];
    const float* wo = (const float*)d_in[6];
    float* out = (float*)d_out;

    // ws (halves): wbf[4M] | xq[8M] | xk[8M] | xvT[8M] | vbf/ao[8M] = 72 MB.
    // qbf/kbf live in d_out (32 MB): dead scratch until out_gemm writes it.
    ushort_t* wbf = (ushort_t*)d_ws;
    ushort_t* xq  = wbf + 4194304ull;
    ushort_t* xk  = xq  + 8388608ull;
    ushort_t* xvT = xk  + 8388608ull;
    ushort_t* ao  = xvT + 8388608ull;
    ushort_t* vbf = ao;
    ushort_t* qbf = (ushort_t*)d_out;
    ushort_t* kbf = qbf + 8388608ull;

    cvt_all<<<14336, 256, 0, stream>>>(q, k, v, wq, wk, wv, wo, qbf, kbf, vbf, wbf);
    proj3f<<<1536, 256, 0, stream>>>(qbf, kbf, vbf, wbf, xq, xk, xvT);
    attn_kernel<<<512, 512, 0, stream>>>(xq, xk, xvT, ao);
    out_gemm<<<256, 512, 0, stream>>>(ao, wbf + 3145728ull, out);
}

// Round 11
// 314.144 us; speedup vs baseline: 1.1280x; 1.0278x over previous
//
#include <hip/hip_runtime.h>

#define SS 2048
#define DD 1024
#define HH 16
#define HD 64
#define MM 8192   // B*S

typedef unsigned short ushort_t;
typedef __attribute__((ext_vector_type(8))) short short8;
typedef __attribute__((ext_vector_type(4))) float f32x4;
typedef __attribute__((ext_vector_type(4))) unsigned short us4;
typedef __attribute__((ext_vector_type(8))) unsigned short us8;

__device__ __forceinline__ ushort_t f2bf(float f) {
    union { float f; unsigned u; } x; x.f = f;
    unsigned r = x.u + 0x7fffu + ((x.u >> 16) & 1u);
    return (ushort_t)(r >> 16);
}
__device__ __forceinline__ float bf2f(ushort_t h) {
    union { unsigned u; float f; } x; x.u = ((unsigned)h) << 16; return x.f;
}
// [hi16(b)<<16 | hi16(a)]: truncating bf16 pack of two fp32, one v_perm
__device__ __forceinline__ unsigned pack_bf2(float a, float b) {
    union { float f; unsigned u; } x, y; x.f = a; y.f = b;
    return __builtin_amdgcn_perm(y.u, x.u, 0x07060302u);
}

// async global->LDS, 16B per lane. LDS dst = wave-uniform base + lane*16.
__device__ __forceinline__ void async16(const void* g, void* l) {
    __builtin_amdgcn_global_load_lds(
        (const __attribute__((address_space(1))) unsigned int*)g,
        (__attribute__((address_space(3))) unsigned int*)l, 16, 0, 0);
}

// ---------------- cvt fp32 -> bf16: q,k,v (8M each) + 4 weights (1M each) ----
// Dedicated memory-bound pass (r0/r9 proved in-GEMM variants lose more).
__global__ void cvt_all(const float* __restrict__ q, const float* __restrict__ k,
                        const float* __restrict__ v, const float* __restrict__ wq,
                        const float* __restrict__ wk, const float* __restrict__ wv,
                        const float* __restrict__ wo, ushort_t* __restrict__ qbf,
                        ushort_t* __restrict__ kbf, ushort_t* __restrict__ vbf,
                        ushort_t* __restrict__ wbf) {
    long i = ((long)blockIdx.x * 256 + threadIdx.x) * 8;
    const float* src; ushort_t* dst;
    if (i < (3l << 23)) {
        int s = (int)(i >> 23);
        long off = i & ((1l << 23) - 1);
        src = ((s == 0) ? q : (s == 1) ? k : v) + off;
        dst = ((s == 0) ? qbf : (s == 1) ? kbf : vbf) + off;
    } else {
        long j = i - (3l << 23);
        int s = (int)(j >> 20);
        src = ((s == 0) ? wq : (s == 1) ? wk : (s == 2) ? wv : wo) + (j & 1048575);
        dst = wbf + j;
    }
    float4 f0 = *(const float4*)src;
    float4 f1 = *(const float4*)(src + 4);
    us8 o;
    o[0] = f2bf(f0.x); o[1] = f2bf(f0.y); o[2] = f2bf(f0.z); o[3] = f2bf(f0.w);
    o[4] = f2bf(f1.x); o[5] = f2bf(f1.y); o[6] = f2bf(f1.z); o[7] = f2bf(f1.w);
    *(us8*)dst = o;
}

// ---------------- epilogue scatter (4x4 acc, 64x64-wave variants) ------------
// mode 0: bf16 [B,H,S,HD]; mode 1: bf16 [B,H,HD,S] with key-permuted S;
// mode 2: fp32 row-major [M,D]
__device__ __forceinline__ void epi_store(int row, int col, float vf, int mode,
                                          void* Yv) {
    if (mode == 2) {
        ((float*)Yv)[(size_t)row * DD + col] = vf;
    } else {
        ushort_t vh = f2bf(vf);
        int b = row >> 11, s = row & 2047;
        int h = col >> 6,  hd = col & 63;
        if (mode == 0) {
            ((ushort_t*)Yv)[(((size_t)b * HH + h) * SS + s) * HD + hd] = vh;
        } else {
            // key k = s%64 stored at pos (k&15)*4 + (k>>4)&3
            int sp = (s & ~63) | (((s & 15) << 2) | ((s >> 4) & 3));
            ((ushort_t*)Yv)[(((size_t)b * HH + h) * HD + hd) * SS + sp] = vh;
        }
    }
}

__device__ __forceinline__ void epi_scatter(f32x4 acc[4][4], int m0, int n0,
                                            int mode, void* Yv) {
    int tid = threadIdx.x;
    int w = tid >> 6, lane = tid & 63;
    int l16 = lane & 15, quad = lane >> 4;
    int wm = (w >> 1) * 64, wn = (w & 1) * 64;
    #pragma unroll
    for (int mt = 0; mt < 4; ++mt)
        #pragma unroll
        for (int r = 0; r < 4; ++r) {
            int row = m0 + wm + mt * 16 + quad * 4 + r;
            #pragma unroll
            for (int nt = 0; nt < 4; ++nt)
                epi_store(row, n0 + wn + nt * 16 + l16, acc[mt][nt][r], mode, Yv);
        }
}

// ---------------- fused projections: 128^2 tile, 8 waves, T4 pipeline --------
// r10 change: 4 -> 8 waves/block at SAME tile/LDS/sync (per-wave 64x32,
// acc[4][2]). Mechanism: double resident waves/CU 12 -> 24 to hide the
// barrier/vmcnt drain that leaves ~60% idle (r6's attn won -18us with the
// same transform). Staging: 1 A + 1 B granule per thread, vmcnt 4/2/0.
__global__ __launch_bounds__(512) void proj3f(const ushort_t* __restrict__ qbf,
                                              const ushort_t* __restrict__ kbf,
                                              const ushort_t* __restrict__ vbf,
                                              const ushort_t* __restrict__ Wall,
                                              ushort_t* __restrict__ xq,
                                              ushort_t* __restrict__ xk,
                                              ushort_t* __restrict__ xvT) {
    __shared__ __align__(16) ushort_t As[3][128 * 32];
    __shared__ __align__(16) ushort_t Bs[3][128 * 32];
    int tid = threadIdx.x;
    int w = tid >> 6, lane = tid & 63;
    int l16 = lane & 15, quad = lane >> 4;
    int mat   = (int)(blockIdx.x >> 9);
    int inner = (int)(blockIdx.x & 511);
    int m0 = (inner & 63) * 128;
    int n0 = (inner >> 6) * 128;
    const ushort_t* A  = (mat == 0) ? qbf : (mat == 1) ? kbf : vbf;
    const ushort_t* Bw = Wall + ((size_t)mat << 20);
    int wm = (w >> 2) * 64, wn = (w & 3) * 32;   // 2M x 4N waves, 64x32 each

    f32x4 acc[4][2];
    #pragma unroll
    for (int i = 0; i < 4; ++i)
        #pragma unroll
        for (int j = 0; j < 2; ++j) acc[i][j] = (f32x4){0.f, 0.f, 0.f, 0.f};

    // staging: 512 granules per tile, 1 per thread (A and B each)
    int r0 = tid >> 2, j0 = ((tid & 3) ^ (r0 & 3)) * 8;
    int swA = (quad ^ (l16 & 3)) * 8;

    const ushort_t* Ar0 = A  + (size_t)(m0 + r0) * DD + j0;
    const ushort_t* Br0 = Bw + (size_t)(n0 + r0) * DD + j0;
    int ldsb = w * 64 * 8;                        // wave-uniform base

    // prologue: stage k=0 -> buf0, k=1 -> buf1 (4 loads outstanding)
    async16(Ar0,      &As[0][ldsb]);
    async16(Br0,      &Bs[0][ldsb]);
    async16(Ar0 + 32, &As[1][ldsb]);
    async16(Br0 + 32, &Bs[1][ldsb]);

    int c = 0, c2 = 2;   // compute buffer, stage-target buffer (= c+2 mod 3)
    for (int kk = 0; kk < 32; ++kk) {
        __builtin_amdgcn_s_barrier();          // iter kk-1 readers of buf c2 done
        if (kk < 30) {
            int k2 = (kk + 2) * 32;
            async16(Ar0 + k2, &As[c2][ldsb]);
            async16(Br0 + k2, &Bs[c2][ldsb]);
            asm volatile("s_waitcnt vmcnt(4)" ::: "memory");   // stage(kk) landed
        } else if (kk == 30) {
            asm volatile("s_waitcnt vmcnt(2)" ::: "memory");
        } else {
            asm volatile("s_waitcnt vmcnt(0)" ::: "memory");
        }
        __builtin_amdgcn_s_barrier();          // ALL waves' stage(kk) landed
        __builtin_amdgcn_sched_barrier(0);

        short8 af[4], bfr[2];
        #pragma unroll
        for (int t = 0; t < 4; ++t)
            af[t] = *(const short8*)&As[c][(wm + t * 16 + l16) * 32 + swA];
        #pragma unroll
        for (int t = 0; t < 2; ++t)
            bfr[t] = *(const short8*)&Bs[c][(wn + t * 16 + l16) * 32 + swA];
        #pragma unroll
        for (int mt = 0; mt < 4; ++mt)
            #pragma unroll
            for (int nt = 0; nt < 2; ++nt)
                acc[mt][nt] = __builtin_amdgcn_mfma_f32_16x16x32_bf16(af[mt], bfr[nt], acc[mt][nt], 0, 0, 0);

        c  = (c  == 2) ? 0 : c  + 1;
        c2 = (c2 == 2) ? 0 : c2 + 1;
    }

    void* Y = (mat == 0) ? (void*)xq : (mat == 1) ? (void*)xk : (void*)xvT;
    int mode = (mat == 2) ? 1 : 0;
    #pragma unroll
    for (int mt = 0; mt < 4; ++mt)
        #pragma unroll
        for (int r = 0; r < 4; ++r) {
            int row = m0 + wm + mt * 16 + quad * 4 + r;
            #pragma unroll
            for (int nt = 0; nt < 2; ++nt)
                epi_store(row, n0 + wn + nt * 16 + l16, acc[mt][nt][r], mode, Y);
        }
}

// ---------------- output GEMM: 256x128 tile, 2-phase, 8 waves ----------------
__global__ __launch_bounds__(512) void out_gemm(const ushort_t* __restrict__ Abf,
                                                const ushort_t* __restrict__ Bw,
                                                float* __restrict__ Y) {
    __shared__ __align__(16) ushort_t As[2][256 * 32];
    __shared__ __align__(16) ushort_t Bs[2][128 * 32];
    int tid = threadIdx.x;
    int w = tid >> 6, lane = tid & 63;
    int l16 = lane & 15, quad = lane >> 4;
    int inner = (int)blockIdx.x;
    int m0 = (inner & 31) * 256;
    int n0 = (inner >> 5) * 128;
    int wm = (w >> 1) * 64, wn = (w & 1) * 64;

    f32x4 acc[4][4];
    #pragma unroll
    for (int i = 0; i < 4; ++i)
        #pragma unroll
        for (int j = 0; j < 4; ++j) acc[i][j] = (f32x4){0.f, 0.f, 0.f, 0.f};

    int ra0 = tid >> 2,           ja0 = ((tid & 3) ^ (ra0 & 3)) * 8;
    int ga1 = tid + 512;
    int ra1 = ga1 >> 2,           ja1 = ((ga1 & 3) ^ (ra1 & 3)) * 8;
    int rb  = tid >> 2,           jb  = ((tid & 3) ^ (rb & 3)) * 8;
    int swA = (quad ^ (l16 & 3)) * 8;

    async16(Abf + (size_t)(m0 + ra0) * DD + ja0, &As[0][(size_t)(w * 64) * 8]);
    async16(Abf + (size_t)(m0 + ra1) * DD + ja1, &As[0][(size_t)(512 + w * 64) * 8]);
    async16(Bw  + (size_t)(n0 + rb)  * DD + jb,  &Bs[0][(size_t)(w * 64) * 8]);

    for (int kk = 0; kk < 32; ++kk) {
        int c = kk & 1;
        __syncthreads();
        if (kk < 31) {
            int k1 = (kk + 1) * 32;
            async16(Abf + (size_t)(m0 + ra0) * DD + k1 + ja0, &As[c ^ 1][(size_t)(w * 64) * 8]);
            async16(Abf + (size_t)(m0 + ra1) * DD + k1 + ja1, &As[c ^ 1][(size_t)(512 + w * 64) * 8]);
            async16(Bw  + (size_t)(n0 + rb)  * DD + k1 + jb,  &Bs[c ^ 1][(size_t)(w * 64) * 8]);
        }
        short8 af[4], bfr[4];
        #pragma unroll
        for (int t = 0; t < 4; ++t) {
            af[t]  = *(const short8*)&As[c][(wm + t * 16 + l16) * 32 + swA];
            bfr[t] = *(const short8*)&Bs[c][(wn + t * 16 + l16) * 32 + swA];
        }
        #pragma unroll
        for (int mt = 0; mt < 4; ++mt)
            #pragma unroll
            for (int nt = 0; nt < 4; ++nt)
                acc[mt][nt] = __builtin_amdgcn_mfma_f32_16x16x32_bf16(af[mt], bfr[nt], acc[mt][nt], 0, 0, 0);
    }
    epi_scatter(acc, m0, n0, 2, Y);
}

// ---------------- Flash attention: QBLK=128, 8 waves (r6-proven) -------------
__global__ __launch_bounds__(512) void attn_kernel(const ushort_t* __restrict__ xq,
                                                   const ushort_t* __restrict__ xk,
                                                   const ushort_t* __restrict__ xvT,
                                                   ushort_t* __restrict__ ao) {
    __shared__ __align__(16) ushort_t Ksm[2][64 * 64];
    __shared__ __align__(16) ushort_t Vsm[2][64 * 64];
    __shared__ __align__(16) ushort_t Psm[8][16 * 72];

    int tid = threadIdx.x;
    int w = tid >> 6, lane = tid & 63;
    int l16 = lane & 15, quad = lane >> 4;
    int bh = blockIdx.x & 63;
    int p  = blockIdx.x >> 6;          // 0..7
    int b = bh >> 4, h = bh & 15;

    const ushort_t* Q  = xq  + (size_t)bh * SS * HD;
    const ushort_t* K  = xk  + (size_t)bh * SS * HD;
    const ushort_t* VT = xvT + (size_t)bh * HD * SS;

    int r0 = tid >> 3, j0 = ((tid & 7) ^ (r0 & 7)) * 8;
    int ldsb = (w * 64) * 8;

    short8 ones;
    #pragma unroll
    for (int i = 0; i < 8; ++i) ones[i] = (short)0x3F80;   // bf16 1.0

    const float CS = 0.125f * 1.44269504f;   // scale * log2(e), folded into Q

    for (int ph = 0; ph < 2; ++ph) {
        int qt = ph ? (15 - p) : p;
        int qb = qt * 128;
        int qmin = qb + w * 16;
        int ktmax = 2 * qt + 1;

        short8 aq[2];
        #pragma unroll
        for (int kc = 0; kc < 2; ++kc) {
            short8 t = *(const short8*)(Q + (size_t)(qmin + l16) * HD + kc * 32 + quad * 8);
            #pragma unroll
            for (int i = 0; i < 8; ++i)
                t[i] = (short)f2bf(bf2f((ushort_t)t[i]) * CS);
            aq[kc] = t;
        }

        f32x4 o[4];
        #pragma unroll
        for (int dt = 0; dt < 4; ++dt) o[dt] = (f32x4){0.f, 0.f, 0.f, 0.f};
        f32x4 lacc = (f32x4){0.f, 0.f, 0.f, 0.f};

        __syncthreads();
        async16(K  + (size_t)r0 * HD + j0, &Ksm[0][ldsb]);
        async16(VT + (size_t)r0 * SS + j0, &Vsm[0][ldsb]);

        for (int kt = 0; kt <= ktmax; ++kt) {
            int kb = kt * 64;
            int c = kt & 1;
            __syncthreads();
            if (kt < ktmax) {
                int kb1 = kb + 64;
                async16(K  + (size_t)(kb1 + r0) * HD + j0, &Ksm[c ^ 1][ldsb]);
                async16(VT + (size_t)r0 * SS + kb1 + j0, &Vsm[c ^ 1][ldsb]);
            }

            f32x4 sc[4];
            __builtin_amdgcn_s_setprio(1);
            #pragma unroll
            for (int nt = 0; nt < 4; ++nt) {
                int row = nt * 16 + l16;
                short8 bk0 = *(const short8*)&Ksm[c][row * 64 + ((0 + quad) ^ (l16 & 7)) * 8];
                short8 bk1 = *(const short8*)&Ksm[c][row * 64 + ((4 + quad) ^ (l16 & 7)) * 8];
                f32x4 cc = (f32x4){0.f, 0.f, 0.f, 0.f};
                cc = __builtin_amdgcn_mfma_f32_16x16x32_bf16(aq[0], bk0, cc, 0, 0, 0);
                cc = __builtin_amdgcn_mfma_f32_16x16x32_bf16(aq[1], bk1, cc, 0, 0, 0);
                sc[nt] = cc;
            }
            __builtin_amdgcn_s_setprio(0);

            bool msk = (kb + 63 > qmin);
            #pragma unroll
            for (int r = 0; r < 4; ++r) {
                float e0, e1, e2, e3;
                if (msk) {
                    int qg = qmin + quad * 4 + r;
                    e0 = (kb +  0 + l16 <= qg) ? __builtin_amdgcn_exp2f(sc[0][r]) : 0.f;
                    e1 = (kb + 16 + l16 <= qg) ? __builtin_amdgcn_exp2f(sc[1][r]) : 0.f;
                    e2 = (kb + 32 + l16 <= qg) ? __builtin_amdgcn_exp2f(sc[2][r]) : 0.f;
                    e3 = (kb + 48 + l16 <= qg) ? __builtin_amdgcn_exp2f(sc[3][r]) : 0.f;
                } else {
                    e0 = __builtin_amdgcn_exp2f(sc[0][r]);
                    e1 = __builtin_amdgcn_exp2f(sc[1][r]);
                    e2 = __builtin_amdgcn_exp2f(sc[2][r]);
                    e3 = __builtin_amdgcn_exp2f(sc[3][r]);
                }
                uint2 pk = { pack_bf2(e0, e1), pack_bf2(e2, e3) };
                *(uint2*)&Psm[w][(quad * 4 + r) * 72 + l16 * 4] = pk;
            }

            asm volatile("s_waitcnt lgkmcnt(0)" ::: "memory");

            __builtin_amdgcn_s_setprio(1);
            #pragma unroll
            for (int kc = 0; kc < 2; ++kc) {
                short8 ap = *(const short8*)&Psm[w][l16 * 72 + kc * 32 + quad * 8];
                lacc = __builtin_amdgcn_mfma_f32_16x16x32_bf16(ap, ones, lacc, 0, 0, 0);
                #pragma unroll
                for (int dt = 0; dt < 4; ++dt) {
                    int row = dt * 16 + l16;
                    short8 bv = *(const short8*)&Vsm[c][row * 64 + ((kc * 4 + quad) ^ (l16 & 7)) * 8];
                    o[dt] = __builtin_amdgcn_mfma_f32_16x16x32_bf16(ap, bv, o[dt], 0, 0, 0);
                }
            }
            __builtin_amdgcn_s_setprio(0);
        }

        #pragma unroll
        for (int r = 0; r < 4; ++r) {
            float inv = 1.0f / lacc[r];
            int qg = qmin + quad * 4 + r;
            #pragma unroll
            for (int dt = 0; dt < 4; ++dt)
                ao[((size_t)(b * SS + qg)) * DD + h * HD + dt * 16 + l16] = f2bf(o[dt][r] * inv);
        }
    }
}

// ---------------------------------------------------------------------------
extern "C" void kernel_launch(void* const* d_in, const int* in_sizes, int n_in,
                              void* d_out, int out_size, void* d_ws, size_t ws_size,
                              hipStream_t stream) {
    const float* q  = (const float*)d_in[0];
    const float* k  = (const float*)d_in[1];
    const float* v  = (const float*)d_in[2];
    const float* wq = (const float*)d_in[3];
    const float* wk = (const float*)d_in[4];
    const float* wv = (const float*)d_in[5];
    const float* wo = (const float*)d_in[6];
    float* out = (float*)d_out;

    // ws (halves): wbf[4M] | xq[8M] | xk[8M] | xvT[8M] | vbf/ao[8M] = 72 MB.
    // qbf/kbf live in d_out (32 MB): dead scratch until out_gemm writes it.
    ushort_t* wbf = (ushort_t*)d_ws;
    ushort_t* xq  = wbf + 4194304ull;
    ushort_t* xk  = xq  + 8388608ull;
    ushort_t* xvT = xk  + 8388608ull;
    ushort_t* ao  = xvT + 8388608ull;
    ushort_t* vbf = ao;
    ushort_t* qbf = (ushort_t*)d_out;
    ushort_t* kbf = qbf + 8388608ull;

    cvt_all<<<14336, 256, 0, stream>>>(q, k, v, wq, wk, wv, wo, qbf, kbf, vbf, wbf);
    proj3f<<<1536, 512, 0, stream>>>(qbf, kbf, vbf, wbf, xq, xk, xvT);
    attn_kernel<<<512, 512, 0, stream>>>(xq, xk, xvT, ao);
    out_gemm<<<256, 512, 0, stream>>>(ao, wbf + 3145728ull, out);
}

// Round 12
// 313.068 us; speedup vs baseline: 1.1319x; 1.0034x over previous
//
#include <hip/hip_runtime.h>

#define SS 2048
#define DD 1024
#define HH 16
#define HD 64
#define MM 8192   // B*S

typedef unsigned short ushort_t;
typedef __attribute__((ext_vector_type(8))) short short8;
typedef __attribute__((ext_vector_type(4))) float f32x4;
typedef __attribute__((ext_vector_type(4))) unsigned short us4;
typedef __attribute__((ext_vector_type(8))) unsigned short us8;

__device__ __forceinline__ ushort_t f2bf(float f) {
    union { float f; unsigned u; } x; x.f = f;
    unsigned r = x.u + 0x7fffu + ((x.u >> 16) & 1u);
    return (ushort_t)(r >> 16);
}
__device__ __forceinline__ float bf2f(ushort_t h) {
    union { unsigned u; float f; } x; x.u = ((unsigned)h) << 16; return x.f;
}
// [hi16(b)<<16 | hi16(a)]: truncating bf16 pack of two fp32, one v_perm
__device__ __forceinline__ unsigned pack_bf2(float a, float b) {
    union { float f; unsigned u; } x, y; x.f = a; y.f = b;
    return __builtin_amdgcn_perm(y.u, x.u, 0x07060302u);
}

// async global->LDS, 16B per lane. LDS dst = wave-uniform base + lane*16.
__device__ __forceinline__ void async16(const void* g, void* l) {
    __builtin_amdgcn_global_load_lds(
        (const __attribute__((address_space(1))) unsigned int*)g,
        (__attribute__((address_space(3))) unsigned int*)l, 16, 0, 0);
}

// ---------------- cvt fp32 -> bf16: q,k,v (8M each) + 4 weights (1M each) ----
// Dedicated memory-bound pass (r0/r9 proved in-GEMM variants lose more).
__global__ void cvt_all(const float* __restrict__ q, const float* __restrict__ k,
                        const float* __restrict__ v, const float* __restrict__ wq,
                        const float* __restrict__ wk, const float* __restrict__ wv,
                        const float* __restrict__ wo, ushort_t* __restrict__ qbf,
                        ushort_t* __restrict__ kbf, ushort_t* __restrict__ vbf,
                        ushort_t* __restrict__ wbf) {
    long i = ((long)blockIdx.x * 256 + threadIdx.x) * 8;
    const float* src; ushort_t* dst;
    if (i < (3l << 23)) {
        int s = (int)(i >> 23);
        long off = i & ((1l << 23) - 1);
        src = ((s == 0) ? q : (s == 1) ? k : v) + off;
        dst = ((s == 0) ? qbf : (s == 1) ? kbf : vbf) + off;
    } else {
        long j = i - (3l << 23);
        int s = (int)(j >> 20);
        src = ((s == 0) ? wq : (s == 1) ? wk : (s == 2) ? wv : wo) + (j & 1048575);
        dst = wbf + j;
    }
    float4 f0 = *(const float4*)src;
    float4 f1 = *(const float4*)(src + 4);
    us8 o;
    o[0] = f2bf(f0.x); o[1] = f2bf(f0.y); o[2] = f2bf(f0.z); o[3] = f2bf(f0.w);
    o[4] = f2bf(f1.x); o[5] = f2bf(f1.y); o[6] = f2bf(f1.z); o[7] = f2bf(f1.w);
    *(us8*)dst = o;
}

// ---------------- epilogue store --------------------------------------------
// mode 0: bf16 [B,H,S,HD]; mode 1: bf16 [B,H,HD,S] with key-permuted S;
// mode 2: fp32 row-major [M,D]
__device__ __forceinline__ void epi_store(int row, int col, float vf, int mode,
                                          void* Yv) {
    if (mode == 2) {
        ((float*)Yv)[(size_t)row * DD + col] = vf;
    } else {
        ushort_t vh = f2bf(vf);
        int b = row >> 11, s = row & 2047;
        int h = col >> 6,  hd = col & 63;
        if (mode == 0) {
            ((ushort_t*)Yv)[(((size_t)b * HH + h) * SS + s) * HD + hd] = vh;
        } else {
            // key k = s%64 stored at pos (k&15)*4 + (k>>4)&3
            int sp = (s & ~63) | (((s & 15) << 2) | ((s >> 4) & 3));
            ((ushort_t*)Yv)[(((size_t)b * HH + h) * HD + hd) * SS + sp] = vh;
        }
    }
}

// ---------------- shared GEMM body: 128^2 tile, 8 waves, T4 pipeline ---------
// r11-verified structure (proj3f 90us, MfmaUtil 23.5, occ 49%): per-wave
// 64x32 (acc[4][2]), 3 LDS buffers, prefetch depth 2, counted vmcnt 4/2/0,
// 1 A + 1 B staging granule per thread.
__device__ __forceinline__ void gemm128_body(const ushort_t* __restrict__ A,
                                             const ushort_t* __restrict__ Bw,
                                             int m0, int n0, int mode, void* Y,
                                             ushort_t (*As)[128 * 32],
                                             ushort_t (*Bs)[128 * 32]) {
    int tid = threadIdx.x;
    int w = tid >> 6, lane = tid & 63;
    int l16 = lane & 15, quad = lane >> 4;
    int wm = (w >> 2) * 64, wn = (w & 3) * 32;   // 2M x 4N waves, 64x32 each

    f32x4 acc[4][2];
    #pragma unroll
    for (int i = 0; i < 4; ++i)
        #pragma unroll
        for (int j = 0; j < 2; ++j) acc[i][j] = (f32x4){0.f, 0.f, 0.f, 0.f};

    int r0 = tid >> 2, j0 = ((tid & 3) ^ (r0 & 3)) * 8;
    int swA = (quad ^ (l16 & 3)) * 8;

    const ushort_t* Ar0 = A  + (size_t)(m0 + r0) * DD + j0;
    const ushort_t* Br0 = Bw + (size_t)(n0 + r0) * DD + j0;
    int ldsb = w * 64 * 8;                        // wave-uniform base

    // prologue: stage k=0 -> buf0, k=1 -> buf1 (4 loads outstanding)
    async16(Ar0,      &As[0][ldsb]);
    async16(Br0,      &Bs[0][ldsb]);
    async16(Ar0 + 32, &As[1][ldsb]);
    async16(Br0 + 32, &Bs[1][ldsb]);

    int c = 0, c2 = 2;   // compute buffer, stage-target buffer (= c+2 mod 3)
    for (int kk = 0; kk < 32; ++kk) {
        __builtin_amdgcn_s_barrier();          // iter kk-1 readers of buf c2 done
        if (kk < 30) {
            int k2 = (kk + 2) * 32;
            async16(Ar0 + k2, &As[c2][ldsb]);
            async16(Br0 + k2, &Bs[c2][ldsb]);
            asm volatile("s_waitcnt vmcnt(4)" ::: "memory");   // stage(kk) landed
        } else if (kk == 30) {
            asm volatile("s_waitcnt vmcnt(2)" ::: "memory");
        } else {
            asm volatile("s_waitcnt vmcnt(0)" ::: "memory");
        }
        __builtin_amdgcn_s_barrier();          // ALL waves' stage(kk) landed
        __builtin_amdgcn_sched_barrier(0);

        short8 af[4], bfr[2];
        #pragma unroll
        for (int t = 0; t < 4; ++t)
            af[t] = *(const short8*)&As[c][(wm + t * 16 + l16) * 32 + swA];
        #pragma unroll
        for (int t = 0; t < 2; ++t)
            bfr[t] = *(const short8*)&Bs[c][(wn + t * 16 + l16) * 32 + swA];
        #pragma unroll
        for (int mt = 0; mt < 4; ++mt)
            #pragma unroll
            for (int nt = 0; nt < 2; ++nt)
                acc[mt][nt] = __builtin_amdgcn_mfma_f32_16x16x32_bf16(af[mt], bfr[nt], acc[mt][nt], 0, 0, 0);

        c  = (c  == 2) ? 0 : c  + 1;
        c2 = (c2 == 2) ? 0 : c2 + 1;
    }

    #pragma unroll
    for (int mt = 0; mt < 4; ++mt)
        #pragma unroll
        for (int r = 0; r < 4; ++r) {
            int row = m0 + wm + mt * 16 + quad * 4 + r;
            #pragma unroll
            for (int nt = 0; nt < 2; ++nt)
                epi_store(row, n0 + wn + nt * 16 + l16, acc[mt][nt][r], mode, Y);
        }
}

// ---------------- fused projections (r11-verified, 90us) ---------------------
__global__ __launch_bounds__(512) void proj3f(const ushort_t* __restrict__ qbf,
                                              const ushort_t* __restrict__ kbf,
                                              const ushort_t* __restrict__ vbf,
                                              const ushort_t* __restrict__ Wall,
                                              ushort_t* __restrict__ xq,
                                              ushort_t* __restrict__ xk,
                                              ushort_t* __restrict__ xvT) {
    __shared__ __align__(16) ushort_t As[3][128 * 32];
    __shared__ __align__(16) ushort_t Bs[3][128 * 32];
    int mat   = (int)(blockIdx.x >> 9);
    int inner = (int)(blockIdx.x & 511);
    int m0 = (inner & 63) * 128;     // XCD swizzle: A-panel sharers on one XCD
    int n0 = (inner >> 6) * 128;
    const ushort_t* A  = (mat == 0) ? qbf : (mat == 1) ? kbf : vbf;
    const ushort_t* Bw = Wall + ((size_t)mat << 20);
    void* Y = (mat == 0) ? (void*)xq : (mat == 1) ? (void*)xk : (void*)xvT;
    gemm128_body(A, Bw, m0, n0, (mat == 2) ? 1 : 0, Y, As, Bs);
}

// ---------------- output GEMM: same r11 structure, grid 512 ------------------
// r11 port: was 256x128/2-phase at 1 block/CU (8 waves/CU — lowest-occupancy
// kernel). Now identical to proj3f's verified body: 2 blocks/CU, 16 waves/CU.
// Per-matrix cost of this structure measured r11: ~30us (90.4/3).
__global__ __launch_bounds__(512) void out_gemm(const ushort_t* __restrict__ Abf,
                                                const ushort_t* __restrict__ Bw,
                                                float* __restrict__ Y) {
    __shared__ __align__(16) ushort_t As[3][128 * 32];
    __shared__ __align__(16) ushort_t Bs[3][128 * 32];
    int m0 = (int)(blockIdx.x & 63) * 128;   // XCD swizzle
    int n0 = (int)(blockIdx.x >> 6) * 128;
    gemm128_body(Abf, Bw, m0, n0, 2, (void*)Y, As, Bs);
}

// ---------------- Flash attention: QBLK=128, 8 waves (r6-proven) -------------
__global__ __launch_bounds__(512) void attn_kernel(const ushort_t* __restrict__ xq,
                                                   const ushort_t* __restrict__ xk,
                                                   const ushort_t* __restrict__ xvT,
                                                   ushort_t* __restrict__ ao) {
    __shared__ __align__(16) ushort_t Ksm[2][64 * 64];
    __shared__ __align__(16) ushort_t Vsm[2][64 * 64];
    __shared__ __align__(16) ushort_t Psm[8][16 * 72];

    int tid = threadIdx.x;
    int w = tid >> 6, lane = tid & 63;
    int l16 = lane & 15, quad = lane >> 4;
    int bh = blockIdx.x & 63;
    int p  = blockIdx.x >> 6;          // 0..7
    int b = bh >> 4, h = bh & 15;

    const ushort_t* Q  = xq  + (size_t)bh * SS * HD;
    const ushort_t* K  = xk  + (size_t)bh * SS * HD;
    const ushort_t* VT = xvT + (size_t)bh * HD * SS;

    int r0 = tid >> 3, j0 = ((tid & 7) ^ (r0 & 7)) * 8;
    int ldsb = (w * 64) * 8;

    short8 ones;
    #pragma unroll
    for (int i = 0; i < 8; ++i) ones[i] = (short)0x3F80;   // bf16 1.0

    const float CS = 0.125f * 1.44269504f;   // scale * log2(e), folded into Q

    for (int ph = 0; ph < 2; ++ph) {
        int qt = ph ? (15 - p) : p;
        int qb = qt * 128;
        int qmin = qb + w * 16;
        int ktmax = 2 * qt + 1;

        short8 aq[2];
        #pragma unroll
        for (int kc = 0; kc < 2; ++kc) {
            short8 t = *(const short8*)(Q + (size_t)(qmin + l16) * HD + kc * 32 + quad * 8);
            #pragma unroll
            for (int i = 0; i < 8; ++i)
                t[i] = (short)f2bf(bf2f((ushort_t)t[i]) * CS);
            aq[kc] = t;
        }

        f32x4 o[4];
        #pragma unroll
        for (int dt = 0; dt < 4; ++dt) o[dt] = (f32x4){0.f, 0.f, 0.f, 0.f};
        f32x4 lacc = (f32x4){0.f, 0.f, 0.f, 0.f};

        __syncthreads();
        async16(K  + (size_t)r0 * HD + j0, &Ksm[0][ldsb]);
        async16(VT + (size_t)r0 * SS + j0, &Vsm[0][ldsb]);

        for (int kt = 0; kt <= ktmax; ++kt) {
            int kb = kt * 64;
            int c = kt & 1;
            __syncthreads();
            if (kt < ktmax) {
                int kb1 = kb + 64;
                async16(K  + (size_t)(kb1 + r0) * HD + j0, &Ksm[c ^ 1][ldsb]);
                async16(VT + (size_t)r0 * SS + kb1 + j0, &Vsm[c ^ 1][ldsb]);
            }

            f32x4 sc[4];
            __builtin_amdgcn_s_setprio(1);
            #pragma unroll
            for (int nt = 0; nt < 4; ++nt) {
                int row = nt * 16 + l16;
                short8 bk0 = *(const short8*)&Ksm[c][row * 64 + ((0 + quad) ^ (l16 & 7)) * 8];
                short8 bk1 = *(const short8*)&Ksm[c][row * 64 + ((4 + quad) ^ (l16 & 7)) * 8];
                f32x4 cc = (f32x4){0.f, 0.f, 0.f, 0.f};
                cc = __builtin_amdgcn_mfma_f32_16x16x32_bf16(aq[0], bk0, cc, 0, 0, 0);
                cc = __builtin_amdgcn_mfma_f32_16x16x32_bf16(aq[1], bk1, cc, 0, 0, 0);
                sc[nt] = cc;
            }
            __builtin_amdgcn_s_setprio(0);

            bool msk = (kb + 63 > qmin);
            #pragma unroll
            for (int r = 0; r < 4; ++r) {
                float e0, e1, e2, e3;
                if (msk) {
                    int qg = qmin + quad * 4 + r;
                    e0 = (kb +  0 + l16 <= qg) ? __builtin_amdgcn_exp2f(sc[0][r]) : 0.f;
                    e1 = (kb + 16 + l16 <= qg) ? __builtin_amdgcn_exp2f(sc[1][r]) : 0.f;
                    e2 = (kb + 32 + l16 <= qg) ? __builtin_amdgcn_exp2f(sc[2][r]) : 0.f;
                    e3 = (kb + 48 + l16 <= qg) ? __builtin_amdgcn_exp2f(sc[3][r]) : 0.f;
                } else {
                    e0 = __builtin_amdgcn_exp2f(sc[0][r]);
                    e1 = __builtin_amdgcn_exp2f(sc[1][r]);
                    e2 = __builtin_amdgcn_exp2f(sc[2][r]);
                    e3 = __builtin_amdgcn_exp2f(sc[3][r]);
                }
                uint2 pk = { pack_bf2(e0, e1), pack_bf2(e2, e3) };
                *(uint2*)&Psm[w][(quad * 4 + r) * 72 + l16 * 4] = pk;
            }

            asm volatile("s_waitcnt lgkmcnt(0)" ::: "memory");

            __builtin_amdgcn_s_setprio(1);
            #pragma unroll
            for (int kc = 0; kc < 2; ++kc) {
                short8 ap = *(const short8*)&Psm[w][l16 * 72 + kc * 32 + quad * 8];
                lacc = __builtin_amdgcn_mfma_f32_16x16x32_bf16(ap, ones, lacc, 0, 0, 0);
                #pragma unroll
                for (int dt = 0; dt < 4; ++dt) {
                    int row = dt * 16 + l16;
                    short8 bv = *(const short8*)&Vsm[c][row * 64 + ((kc * 4 + quad) ^ (l16 & 7)) * 8];
                    o[dt] = __builtin_amdgcn_mfma_f32_16x16x32_bf16(ap, bv, o[dt], 0, 0, 0);
                }
            }
            __builtin_amdgcn_s_setprio(0);
        }

        #pragma unroll
        for (int r = 0; r < 4; ++r) {
            float inv = 1.0f / lacc[r];
            int qg = qmin + quad * 4 + r;
            #pragma unroll
            for (int dt = 0; dt < 4; ++dt)
                ao[((size_t)(b * SS + qg)) * DD + h * HD + dt * 16 + l16] = f2bf(o[dt][r] * inv);
        }
    }
}

// ---------------------------------------------------------------------------
extern "C" void kernel_launch(void* const* d_in, const int* in_sizes, int n_in,
                              void* d_out, int out_size, void* d_ws, size_t ws_size,
                              hipStream_t stream) {
    const float* q  = (const float*)d_in[0];
    const float* k  = (const float*)d_in[1];
    const float* v  = (const float*)d_in[2];
    const float* wq = (const float*)d_in[3];
    const float* wk = (const float*)d_in[4];
    const float* wv = (const float*)d_in[5];
    const float* wo = (const float*)d_in[6];
    float* out = (float*)d_out;

    // ws (halves): wbf[4M] | xq[8M] | xk[8M] | xvT[8M] | vbf/ao[8M] = 72 MB.
    // qbf/kbf live in d_out (32 MB): dead scratch until out_gemm writes it.
    ushort_t* wbf = (ushort_t*)d_ws;
    ushort_t* xq  = wbf + 4194304ull;
    ushort_t* xk  = xq  + 8388608ull;
    ushort_t* xvT = xk  + 8388608ull;
    ushort_t* ao  = xvT + 8388608ull;
    ushort_t* vbf = ao;
    ushort_t* qbf = (ushort_t*)d_out;
    ushort_t* kbf = qbf + 8388608ull;

    cvt_all<<<14336, 256, 0, stream>>>(q, k, v, wq, wk, wv, wo, qbf, kbf, vbf, wbf);
    proj3f<<<1536, 512, 0, stream>>>(qbf, kbf, vbf, wbf, xq, xk, xvT);
    attn_kernel<<<512, 512, 0, stream>>>(xq, xk, xvT, ao);
    out_gemm<<<512, 512, 0, stream>>>(ao, wbf + 3145728ull, out);
}